// Round 9
// baseline (76.719 us; speedup 1.0000x reference)
//
#include <hip/hip_runtime.h>

#define NB 32
#define NS 2048
#define NH 1024
#define WIN 15   // exp(sc-lse-0.5*d^2): score-lse<=0 -> |d|>15 underflows to 0.0f (matches ref)

// ---------------- K1: v[b,h] = sum_d dec[b,d]*Wa[d,h]; zero denomD.
// grid = 16 ht * 32 b (b fastest -> 32 co-scheduled blocks share one Wa tile in L2)
__global__ __launch_bounds__(256) void k1_v(const float* __restrict__ dec,
                                            const float* __restrict__ Wa,
                                            float* __restrict__ v,
                                            double* __restrict__ denomD) {
    __shared__ float red[256];
    int blk = blockIdx.x;
    int b = blk & 31, ht = blk >> 5;
    int t = threadIdx.x;
    if (blk == 0 && t < NB) denomD[t] = 0.0;

    int ds = t >> 6, hl = t & 63;
    int h = ht * 64 + hl;
    const float* decb = dec + b * NH + ds * 256;
    const float* wa   = Wa + (size_t)(ds * 256) * NH + h;
    float a0 = 0.f, a1 = 0.f, a2 = 0.f, a3 = 0.f;
#pragma unroll 2
    for (int d = 0; d < 256; d += 4) {             // 4 split accumulators: no dep chain
        a0 = fmaf(decb[d],     wa[(size_t)d * NH],       a0);
        a1 = fmaf(decb[d + 1], wa[(size_t)(d + 1) * NH], a1);
        a2 = fmaf(decb[d + 2], wa[(size_t)(d + 2) * NH], a2);
        a3 = fmaf(decb[d + 3], wa[(size_t)(d + 3) * NH], a3);
    }
    red[t] = (a0 + a1) + (a2 + a3);
    __syncthreads();
    if (t < 64)
        v[b * NH + ht * 64 + t] = red[t] + red[t + 64] + red[t + 128] + red[t + 192];
}

__device__ __forceinline__ float dot16(float4 x0, float4 x1, float4 x2, float4 x3,
                                       float4 v0, float4 v1, float4 v2, float4 v3) {
    float s = 0.f;
    s = fmaf(x0.x, v0.x, s); s = fmaf(x0.y, v0.y, s); s = fmaf(x0.z, v0.z, s); s = fmaf(x0.w, v0.w, s);
    s = fmaf(x1.x, v1.x, s); s = fmaf(x1.y, v1.y, s); s = fmaf(x1.z, v1.z, s); s = fmaf(x1.w, v1.w, s);
    s = fmaf(x2.x, v2.x, s); s = fmaf(x2.y, v2.y, s); s = fmaf(x2.z, v2.z, s); s = fmaf(x2.w, v2.w, s);
    s = fmaf(x3.x, v3.x, s); s = fmaf(x3.y, v3.y, s); s = fmaf(x3.z, v3.z, s); s = fmaf(x3.w, v3.w, s);
    return s;
}

// ---------------- K2: scores[b,s] = enc[b,s,:].v[b,:]; per-block f64 denom atomic.
// 2 rows/wave with ALL 8 dwordx4 loads issued as one upfront burst (named regs,
// ~70 VGPR -> occupancy preserved). 512 thr = 8 waves = 16 rows/block, 4096 blocks.
__global__ __launch_bounds__(512) void k2_scores(const float* __restrict__ enc,
                                                 const float* __restrict__ v,
                                                 float* __restrict__ scores,
                                                 double* __restrict__ denomD) {
    __shared__ float vs[NH];
    __shared__ float rowsc[16];
    int t = threadIdx.x, wid = t >> 6, lane = t & 63;
    int b = blockIdx.x >> 7;           // 128 blocks per b
    int row0 = blockIdx.x << 4;        // global row (b*NS + s)

    if (t < 256) ((float4*)vs)[t] = ((const float4*)(v + b * NH))[t];
    __syncthreads();
    const float4* vv = (const float4*)vs;
    float4 vr0 = vv[lane], vr1 = vv[64 + lane], vr2 = vv[128 + lane], vr3 = vv[192 + lane];

    int r0 = row0 + wid * 2;
    const float4* eb = (const float4*)(enc + (size_t)r0 * NH);

    // one burst: 8 independent dwordx4 (2 full rows) in flight
    float4 x0 = eb[lane],       x1 = eb[64 + lane],  x2 = eb[128 + lane], x3 = eb[192 + lane];
    float4 y0 = eb[256 + lane], y1 = eb[320 + lane], y2 = eb[384 + lane], y3 = eb[448 + lane];

    float s0 = dot16(x0, x1, x2, x3, vr0, vr1, vr2, vr3);
    float s1 = dot16(y0, y1, y2, y3, vr0, vr1, vr2, vr3);

#pragma unroll
    for (int off = 32; off >= 1; off >>= 1) {
        s0 += __shfl_xor(s0, off, 64);
        s1 += __shfl_xor(s1, off, 64);
    }
    if (lane == 0) {
        scores[r0]     = s0;  rowsc[wid * 2]     = s0;
        scores[r0 + 1] = s1;  rowsc[wid * 2 + 1] = s1;
    }
    __syncthreads();
    if (t < 16) {                       // 16 row-partials -> one f64 atomic
        double e = exp((double)rowsc[t]);
#pragma unroll
        for (int off = 8; off >= 1; off >>= 1) e += __shfl_xor(e, off, 64);
        if (t == 0) atomicAdd(&denomD[b], e);
    }
}

// ---------------- K3: attn = exp(score - lse - 0.5 d^2); owner-chunk computes whole
// ctx window directly (no atomics, no zero-init). grid = 32 b * 8 s-chunks.
__global__ __launch_bounds__(256) void k3_out(const float* __restrict__ enc,
                                              const float* __restrict__ scores,
                                              const int* __restrict__ ts,
                                              const double* __restrict__ denomD,
                                              float* __restrict__ ctx,
                                              float* __restrict__ attn) {
    int b = blockIdx.x >> 3;
    int c = blockIdx.x & 7;
    int t = threadIdx.x;

    float lse = (float)log(denomD[b]);
    int p = ts[b];
    float pf = (float)p;

    int s = c * 256 + t;
    float sc = scores[b * NS + s];
    float d = (float)s - pf;
    attn[(size_t)b * NS + s] = expf(sc - lse - 0.5f * d * d);

    if ((p >> 8) == c) {               // owner chunk: full window, direct store
        int w0 = max(0, p - WIN), w1 = min(NS - 1, p + WIN);
        const float* sb = scores + (size_t)b * NS;
        float a0 = 0.f, a1 = 0.f, a2 = 0.f, a3 = 0.f;
        for (int r = w0; r <= w1; ++r) {
            float dr = (float)r - pf;
            float w = expf(sb[r] - lse - 0.5f * dr * dr);
            const float* er = enc + ((size_t)b * NS + r) * NH;
            a0 = fmaf(w, er[t],       a0);
            a1 = fmaf(w, er[t + 256], a1);
            a2 = fmaf(w, er[t + 512], a2);
            a3 = fmaf(w, er[t + 768], a3);
        }
        ctx[b * NH + t]       = a0;
        ctx[b * NH + t + 256] = a1;
        ctx[b * NH + t + 512] = a2;
        ctx[b * NH + t + 768] = a3;
    }
}

extern "C" void kernel_launch(void* const* d_in, const int* in_sizes, int n_in,
                              void* d_out, int out_size, void* d_ws, size_t ws_size,
                              hipStream_t stream) {
    const float* enc  = (const float*)d_in[0];   // [B,S,H]
    const float* dec  = (const float*)d_in[1];   // [B,H]
    const int*   ts   = (const int*)d_in[2];     // [B]
    const float* Wa_w = (const float*)d_in[3];   // [H,H]
    // d_in[4] = Wa_b: uniform per-b score shift -> softmax-invariant, dropped.

    float* out  = (float*)d_out;
    float* ctx  = out;             // [B,H]
    float* attn = out + NB * NH;   // [B,S]

    float*  v      = (float*)d_ws;                  // NB*NH floats
    float*  scores = v + NB * NH;                   // NB*NS floats
    double* denomD = (double*)(scores + NB * NS);   // NB doubles (8B-aligned)

    k1_v     <<<512,  256, 0, stream>>>(dec, Wa_w, v, denomD);
    k2_scores<<<4096, 512, 0, stream>>>(enc, v, scores, denomD);
    k3_out   <<<NB*8, 256, 0, stream>>>(enc, scores, ts, denomD, ctx, attn);
}

// Round 10
// 72.347 us; speedup vs baseline: 1.0604x; 1.0604x over previous
//
#include <hip/hip_runtime.h>

#define NB 32
#define NS 2048
#define NH 1024
#define WIN 15   // exp(sc-lse-0.5*d^2): score-lse<=0 -> |d|>15 underflows to 0.0f (matches ref)

// ---------------- K1: v[b,h] = sum_d dec[b,d]*Wa[d,h]; zero denomD.
// grid = 16 ht * 32 b (b fastest -> 32 co-scheduled blocks share one Wa tile in L2)
__global__ __launch_bounds__(256) void k1_v(const float* __restrict__ dec,
                                            const float* __restrict__ Wa,
                                            float* __restrict__ v,
                                            double* __restrict__ denomD) {
    __shared__ float red[256];
    int blk = blockIdx.x;
    int b = blk & 31, ht = blk >> 5;
    int t = threadIdx.x;
    if (blk == 0 && t < NB) denomD[t] = 0.0;

    int ds = t >> 6, hl = t & 63;
    int h = ht * 64 + hl;
    const float* decb = dec + b * NH + ds * 256;
    const float* wa   = Wa + (size_t)(ds * 256) * NH + h;
    float a0 = 0.f, a1 = 0.f, a2 = 0.f, a3 = 0.f;
#pragma unroll 2
    for (int d = 0; d < 256; d += 4) {             // 4 split accumulators: no dep chain
        a0 = fmaf(decb[d],     wa[(size_t)d * NH],       a0);
        a1 = fmaf(decb[d + 1], wa[(size_t)(d + 1) * NH], a1);
        a2 = fmaf(decb[d + 2], wa[(size_t)(d + 2) * NH], a2);
        a3 = fmaf(decb[d + 3], wa[(size_t)(d + 3) * NH], a3);
    }
    red[t] = (a0 + a1) + (a2 + a3);
    __syncthreads();
    if (t < 64)
        v[b * NH + ht * 64 + t] = red[t] + red[t + 64] + red[t + 128] + red[t + 192];
}

// ---------------- K2: scores[b,s] = enc[b,s,:].v[b,:]; per-block f64 denom atomic.
// Round-8 hot loop (LDS-staged v -> 16 regs, 4 rows/wave, row-serial compiler-
// scheduled loads). 64 rows/block = two 32-row tiles, 512 thr, 1024 blocks
// (32 per b): v staged ONCE per 64 rows by all threads, ONE atomic per block,
// exactly 4 blocks/CU = single occupancy generation.
__global__ __launch_bounds__(512) void k2_scores(const float* __restrict__ enc,
                                                 const float* __restrict__ v,
                                                 float* __restrict__ scores,
                                                 double* __restrict__ denomD) {
    __shared__ float vs[NH];
    __shared__ float rowsc[64];
    int t = threadIdx.x, wid = t >> 6, lane = t & 63;
    int b = blockIdx.x >> 5;           // 32 blocks per b
    int row0 = blockIdx.x << 6;        // 64 global rows per block

    ((float2*)vs)[t] = ((const float2*)(v + b * NH))[t];   // all 512 threads stage
    __syncthreads();
    const float4* vv = (const float4*)vs;
    float4 vr0 = vv[lane], vr1 = vv[64 + lane], vr2 = vv[128 + lane], vr3 = vv[192 + lane];

#pragma unroll
    for (int tile = 0; tile < 2; ++tile) {
        int r0 = row0 + tile * 32 + wid * 4;
        const float4* eb = (const float4*)(enc + (size_t)r0 * NH);
        float acc[4];
#pragma unroll
        for (int r = 0; r < 4; ++r) {
            float4 x0 = eb[r * 256 + lane];
            float4 x1 = eb[r * 256 + 64 + lane];
            float4 x2 = eb[r * 256 + 128 + lane];
            float4 x3 = eb[r * 256 + 192 + lane];
            float s = 0.f;
            s = fmaf(x0.x, vr0.x, s); s = fmaf(x0.y, vr0.y, s);
            s = fmaf(x0.z, vr0.z, s); s = fmaf(x0.w, vr0.w, s);
            s = fmaf(x1.x, vr1.x, s); s = fmaf(x1.y, vr1.y, s);
            s = fmaf(x1.z, vr1.z, s); s = fmaf(x1.w, vr1.w, s);
            s = fmaf(x2.x, vr2.x, s); s = fmaf(x2.y, vr2.y, s);
            s = fmaf(x2.z, vr2.z, s); s = fmaf(x2.w, vr2.w, s);
            s = fmaf(x3.x, vr3.x, s); s = fmaf(x3.y, vr3.y, s);
            s = fmaf(x3.z, vr3.z, s); s = fmaf(x3.w, vr3.w, s);
            acc[r] = s;
        }
#pragma unroll
        for (int r = 0; r < 4; ++r) {
#pragma unroll
            for (int off = 32; off >= 1; off >>= 1) acc[r] += __shfl_xor(acc[r], off, 64);
            if (lane == 0) {
                scores[r0 + r] = acc[r];
                rowsc[tile * 32 + wid * 4 + r] = acc[r];   // distinct slots, no race
            }
        }
    }
    __syncthreads();
    if (t < 64) {                       // wave 0: 64 row-partials -> one f64 atomic
        double e = exp((double)rowsc[t]);
#pragma unroll
        for (int off = 32; off >= 1; off >>= 1) e += __shfl_xor(e, off, 64);
        if (t == 0) atomicAdd(&denomD[b], e);
    }
}

// ---------------- K3: attn = exp(score - lse - 0.5 d^2); owner-chunk computes whole
// ctx window directly (no atomics, no zero-init). grid = 32 b * 8 s-chunks.
__global__ __launch_bounds__(256) void k3_out(const float* __restrict__ enc,
                                              const float* __restrict__ scores,
                                              const int* __restrict__ ts,
                                              const double* __restrict__ denomD,
                                              float* __restrict__ ctx,
                                              float* __restrict__ attn) {
    int b = blockIdx.x >> 3;
    int c = blockIdx.x & 7;
    int t = threadIdx.x;

    float lse = (float)log(denomD[b]);
    int p = ts[b];
    float pf = (float)p;

    int s = c * 256 + t;
    float sc = scores[b * NS + s];
    float d = (float)s - pf;
    attn[(size_t)b * NS + s] = expf(sc - lse - 0.5f * d * d);

    if ((p >> 8) == c) {               // owner chunk: full window, direct store
        int w0 = max(0, p - WIN), w1 = min(NS - 1, p + WIN);
        const float* sb = scores + (size_t)b * NS;
        float a0 = 0.f, a1 = 0.f, a2 = 0.f, a3 = 0.f;
        for (int r = w0; r <= w1; ++r) {
            float dr = (float)r - pf;
            float w = expf(sb[r] - lse - 0.5f * dr * dr);
            const float* er = enc + ((size_t)b * NS + r) * NH;
            a0 = fmaf(w, er[t],       a0);
            a1 = fmaf(w, er[t + 256], a1);
            a2 = fmaf(w, er[t + 512], a2);
            a3 = fmaf(w, er[t + 768], a3);
        }
        ctx[b * NH + t]       = a0;
        ctx[b * NH + t + 256] = a1;
        ctx[b * NH + t + 512] = a2;
        ctx[b * NH + t + 768] = a3;
    }
}

extern "C" void kernel_launch(void* const* d_in, const int* in_sizes, int n_in,
                              void* d_out, int out_size, void* d_ws, size_t ws_size,
                              hipStream_t stream) {
    const float* enc  = (const float*)d_in[0];   // [B,S,H]
    const float* dec  = (const float*)d_in[1];   // [B,H]
    const int*   ts   = (const int*)d_in[2];     // [B]
    const float* Wa_w = (const float*)d_in[3];   // [H,H]
    // d_in[4] = Wa_b: uniform per-b score shift -> softmax-invariant, dropped.

    float* out  = (float*)d_out;
    float* ctx  = out;             // [B,H]
    float* attn = out + NB * NH;   // [B,S]

    float*  v      = (float*)d_ws;                  // NB*NH floats
    float*  scores = v + NB * NH;                   // NB*NS floats
    double* denomD = (double*)(scores + NB * NS);   // NB doubles (8B-aligned)

    k1_v     <<<512,  256, 0, stream>>>(dec, Wa_w, v, denomD);
    k2_scores<<<1024, 512, 0, stream>>>(enc, v, scores, denomD);
    k3_out   <<<NB*8, 256, 0, stream>>>(enc, scores, ts, denomD, ctx, attn);
}

// Round 11
// 68.467 us; speedup vs baseline: 1.1205x; 1.0567x over previous
//
#include <hip/hip_runtime.h>

#define NB 32
#define NS 2048
#define NH 1024
#define WIN 15   // exp(sc-lse-0.5*d^2): score-lse<=0 -> |d|>15 underflows to 0.0f (matches ref)

// ---------------- K1: v[b,h] = sum_d dec[b,d]*Wa[d,h]; zero denomD.
// float4-over-h: wave-load = 1KB coalesced (16x fewer requests than scalar).
// grid = 4 ht * 32 b (b fastest -> 32 co-scheduled blocks share one Wa tile in L2)
__global__ __launch_bounds__(256) void k1_v(const float* __restrict__ dec,
                                            const float* __restrict__ Wa,
                                            float* __restrict__ v,
                                            double* __restrict__ denomD) {
    __shared__ float4 red4[256];
    int blk = blockIdx.x;
    int b = blk & 31, ht = blk >> 5;   // ht 0..3
    int t = threadIdx.x;
    if (blk == 0 && t < NB) denomD[t] = 0.0;

    int ds = t >> 6, hl = t & 63;      // ds = wave id (d-slice), hl = lane
    int h = ht * 256 + hl * 4;
    const float* decb = dec + b * NH + ds * 256;
    const float* wa   = Wa + (size_t)(ds * 256) * NH + h;

    float4 accA = {0.f, 0.f, 0.f, 0.f}, accB = {0.f, 0.f, 0.f, 0.f};
#pragma unroll 4
    for (int d = 0; d < 256; d += 2) {   // 2 split float4 accumulators
        float sA = decb[d];              // wave-uniform -> s_load
        float sB = decb[d + 1];
        float4 wA = *(const float4*)(wa + (size_t)d * NH);
        float4 wB = *(const float4*)(wa + (size_t)(d + 1) * NH);
        accA.x = fmaf(sA, wA.x, accA.x); accA.y = fmaf(sA, wA.y, accA.y);
        accA.z = fmaf(sA, wA.z, accA.z); accA.w = fmaf(sA, wA.w, accA.w);
        accB.x = fmaf(sB, wB.x, accB.x); accB.y = fmaf(sB, wB.y, accB.y);
        accB.z = fmaf(sB, wB.z, accB.z); accB.w = fmaf(sB, wB.w, accB.w);
    }
    float4 acc = {accA.x + accB.x, accA.y + accB.y, accA.z + accB.z, accA.w + accB.w};
    red4[t] = acc;
    __syncthreads();
    if (t < 64) {
        float4 r0 = red4[t], r1 = red4[t + 64], r2 = red4[t + 128], r3 = red4[t + 192];
        float4 r = {r0.x + r1.x + r2.x + r3.x, r0.y + r1.y + r2.y + r3.y,
                    r0.z + r1.z + r2.z + r3.z, r0.w + r1.w + r2.w + r3.w};
        *(float4*)(v + b * NH + ht * 256 + t * 4) = r;
    }
}

// ---------------- K2: scores[b,s] = enc[b,s,:].v[b,:]; per-block f64 denom atomic.
// (unchanged from round 10) 64 rows/block, 512 thr, 1024 blocks, 4 rows/wave,
// LDS-staged v -> 16 regs, row-serial compiler-scheduled loads, one atomic/block.
__global__ __launch_bounds__(512) void k2_scores(const float* __restrict__ enc,
                                                 const float* __restrict__ v,
                                                 float* __restrict__ scores,
                                                 double* __restrict__ denomD) {
    __shared__ float vs[NH];
    __shared__ float rowsc[64];
    int t = threadIdx.x, wid = t >> 6, lane = t & 63;
    int b = blockIdx.x >> 5;           // 32 blocks per b
    int row0 = blockIdx.x << 6;        // 64 global rows per block

    ((float2*)vs)[t] = ((const float2*)(v + b * NH))[t];   // all 512 threads stage
    __syncthreads();
    const float4* vv = (const float4*)vs;
    float4 vr0 = vv[lane], vr1 = vv[64 + lane], vr2 = vv[128 + lane], vr3 = vv[192 + lane];

#pragma unroll
    for (int tile = 0; tile < 2; ++tile) {
        int r0 = row0 + tile * 32 + wid * 4;
        const float4* eb = (const float4*)(enc + (size_t)r0 * NH);
        float acc[4];
#pragma unroll
        for (int r = 0; r < 4; ++r) {
            float4 x0 = eb[r * 256 + lane];
            float4 x1 = eb[r * 256 + 64 + lane];
            float4 x2 = eb[r * 256 + 128 + lane];
            float4 x3 = eb[r * 256 + 192 + lane];
            float s = 0.f;
            s = fmaf(x0.x, vr0.x, s); s = fmaf(x0.y, vr0.y, s);
            s = fmaf(x0.z, vr0.z, s); s = fmaf(x0.w, vr0.w, s);
            s = fmaf(x1.x, vr1.x, s); s = fmaf(x1.y, vr1.y, s);
            s = fmaf(x1.z, vr1.z, s); s = fmaf(x1.w, vr1.w, s);
            s = fmaf(x2.x, vr2.x, s); s = fmaf(x2.y, vr2.y, s);
            s = fmaf(x2.z, vr2.z, s); s = fmaf(x2.w, vr2.w, s);
            s = fmaf(x3.x, vr3.x, s); s = fmaf(x3.y, vr3.y, s);
            s = fmaf(x3.z, vr3.z, s); s = fmaf(x3.w, vr3.w, s);
            acc[r] = s;
        }
#pragma unroll
        for (int r = 0; r < 4; ++r) {
#pragma unroll
            for (int off = 32; off >= 1; off >>= 1) acc[r] += __shfl_xor(acc[r], off, 64);
            if (lane == 0) {
                scores[r0 + r] = acc[r];
                rowsc[tile * 32 + wid * 4 + r] = acc[r];
            }
        }
    }
    __syncthreads();
    if (t < 64) {                       // wave 0: 64 row-partials -> one f64 atomic
        double e = exp((double)rowsc[t]);
#pragma unroll
        for (int off = 32; off >= 1; off >>= 1) e += __shfl_xor(e, off, 64);
        if (t == 0) atomicAdd(&denomD[b], e);
    }
}

// ---------------- K3: attn = exp(score - lse - 0.5 d^2); owner-chunk computes whole
// ctx window (weights precomputed once into LDS). grid = 32 b * 8 s-chunks.
__global__ __launch_bounds__(256) void k3_out(const float* __restrict__ enc,
                                              const float* __restrict__ scores,
                                              const int* __restrict__ ts,
                                              const double* __restrict__ denomD,
                                              float* __restrict__ ctx,
                                              float* __restrict__ attn) {
    __shared__ float wv[32];
    int b = blockIdx.x >> 3;
    int c = blockIdx.x & 7;
    int t = threadIdx.x;

    float lse = (float)log(denomD[b]);
    int p = ts[b];
    float pf = (float)p;

    int s = c * 256 + t;
    float sc = scores[b * NS + s];
    float d = (float)s - pf;
    attn[(size_t)b * NS + s] = expf(sc - lse - 0.5f * d * d);

    if ((p >> 8) == c) {               // owner chunk (block-uniform): full window
        int w0 = max(0, p - WIN), w1 = min(NS - 1, p + WIN);
        int nw = w1 - w0 + 1;
        const float* sb = scores + (size_t)b * NS;
        if (t < nw) {                  // precompute weights once (no per-thread expf loop)
            float dr = (float)(w0 + t) - pf;
            wv[t] = expf(sb[w0 + t] - lse - 0.5f * dr * dr);
        }
        __syncthreads();
        float a0 = 0.f, a1 = 0.f, a2 = 0.f, a3 = 0.f;
        for (int r = 0; r < nw; ++r) {
            float w = wv[r];
            const float* er = enc + ((size_t)b * NS + w0 + r) * NH;
            a0 = fmaf(w, er[t],       a0);
            a1 = fmaf(w, er[t + 256], a1);
            a2 = fmaf(w, er[t + 512], a2);
            a3 = fmaf(w, er[t + 768], a3);
        }
        ctx[b * NH + t]       = a0;
        ctx[b * NH + t + 256] = a1;
        ctx[b * NH + t + 512] = a2;
        ctx[b * NH + t + 768] = a3;
    }
}

extern "C" void kernel_launch(void* const* d_in, const int* in_sizes, int n_in,
                              void* d_out, int out_size, void* d_ws, size_t ws_size,
                              hipStream_t stream) {
    const float* enc  = (const float*)d_in[0];   // [B,S,H]
    const float* dec  = (const float*)d_in[1];   // [B,H]
    const int*   ts   = (const int*)d_in[2];     // [B]
    const float* Wa_w = (const float*)d_in[3];   // [H,H]
    // d_in[4] = Wa_b: uniform per-b score shift -> softmax-invariant, dropped.

    float* out  = (float*)d_out;
    float* ctx  = out;             // [B,H]
    float* attn = out + NB * NH;   // [B,S]

    float*  v      = (float*)d_ws;                  // NB*NH floats
    float*  scores = v + NB * NH;                   // NB*NS floats
    double* denomD = (double*)(scores + NB * NS);   // NB doubles (8B-aligned)

    k1_v     <<<128,  256, 0, stream>>>(dec, Wa_w, v, denomD);
    k2_scores<<<1024, 512, 0, stream>>>(enc, v, scores, denomD);
    k3_out   <<<NB*8, 256, 0, stream>>>(enc, scores, ts, denomD, ctx, attn);
}

// Round 12
// 66.936 us; speedup vs baseline: 1.1462x; 1.0229x over previous
//
#include <hip/hip_runtime.h>

#define NB 32
#define NS 2048
#define NH 1024
#define WIN 15   // exp(sc-lse-0.5*d^2): score-lse<=0 -> |d|>15 underflows to 0.0f (matches ref)

// ---------------- K1: v[b,h] = sum_d dec[b,d]*Wa[d,h]; zero denomD.
// float4-over-h: wave-load = 1KB coalesced. grid = 4 ht * 32 b.
__global__ __launch_bounds__(256) void k1_v(const float* __restrict__ dec,
                                            const float* __restrict__ Wa,
                                            float* __restrict__ v,
                                            double* __restrict__ denomD) {
    __shared__ float4 red4[256];
    int blk = blockIdx.x;
    int b = blk & 31, ht = blk >> 5;   // ht 0..3
    int t = threadIdx.x;
    if (blk == 0 && t < NB) denomD[t] = 0.0;

    int ds = t >> 6, hl = t & 63;      // ds = wave id (d-slice), hl = lane
    int h = ht * 256 + hl * 4;
    const float* decb = dec + b * NH + ds * 256;
    const float* wa   = Wa + (size_t)(ds * 256) * NH + h;

    float4 accA = {0.f, 0.f, 0.f, 0.f}, accB = {0.f, 0.f, 0.f, 0.f};
#pragma unroll 4
    for (int d = 0; d < 256; d += 2) {   // 2 split float4 accumulators
        float sA = decb[d];              // wave-uniform -> s_load
        float sB = decb[d + 1];
        float4 wA = *(const float4*)(wa + (size_t)d * NH);
        float4 wB = *(const float4*)(wa + (size_t)(d + 1) * NH);
        accA.x = fmaf(sA, wA.x, accA.x); accA.y = fmaf(sA, wA.y, accA.y);
        accA.z = fmaf(sA, wA.z, accA.z); accA.w = fmaf(sA, wA.w, accA.w);
        accB.x = fmaf(sB, wB.x, accB.x); accB.y = fmaf(sB, wB.y, accB.y);
        accB.z = fmaf(sB, wB.z, accB.z); accB.w = fmaf(sB, wB.w, accB.w);
    }
    float4 acc = {accA.x + accB.x, accA.y + accB.y, accA.z + accB.z, accA.w + accB.w};
    red4[t] = acc;
    __syncthreads();
    if (t < 64) {
        float4 r0 = red4[t], r1 = red4[t + 64], r2 = red4[t + 128], r3 = red4[t + 192];
        float4 r = {r0.x + r1.x + r2.x + r3.x, r0.y + r1.y + r2.y + r3.y,
                    r0.z + r1.z + r2.z + r3.z, r0.w + r1.w + r2.w + r3.w};
        *(float4*)(v + b * NH + ht * 256 + t * 4) = r;
    }
}

// ---------------- K2: scores[b,s] = enc[b,s,:].v[b,:]; per-block f64 denom atomic.
// (unchanged from round 10/11) 64 rows/block, 512 thr, 1024 blocks, 4 rows/wave,
// LDS-staged v -> 16 regs, row-serial compiler-scheduled loads, one atomic/block.
__global__ __launch_bounds__(512) void k2_scores(const float* __restrict__ enc,
                                                 const float* __restrict__ v,
                                                 float* __restrict__ scores,
                                                 double* __restrict__ denomD) {
    __shared__ float vs[NH];
    __shared__ float rowsc[64];
    int t = threadIdx.x, wid = t >> 6, lane = t & 63;
    int b = blockIdx.x >> 5;           // 32 blocks per b
    int row0 = blockIdx.x << 6;        // 64 global rows per block

    ((float2*)vs)[t] = ((const float2*)(v + b * NH))[t];   // all 512 threads stage
    __syncthreads();
    const float4* vv = (const float4*)vs;
    float4 vr0 = vv[lane], vr1 = vv[64 + lane], vr2 = vv[128 + lane], vr3 = vv[192 + lane];

#pragma unroll
    for (int tile = 0; tile < 2; ++tile) {
        int r0 = row0 + tile * 32 + wid * 4;
        const float4* eb = (const float4*)(enc + (size_t)r0 * NH);
        float acc[4];
#pragma unroll
        for (int r = 0; r < 4; ++r) {
            float4 x0 = eb[r * 256 + lane];
            float4 x1 = eb[r * 256 + 64 + lane];
            float4 x2 = eb[r * 256 + 128 + lane];
            float4 x3 = eb[r * 256 + 192 + lane];
            float s = 0.f;
            s = fmaf(x0.x, vr0.x, s); s = fmaf(x0.y, vr0.y, s);
            s = fmaf(x0.z, vr0.z, s); s = fmaf(x0.w, vr0.w, s);
            s = fmaf(x1.x, vr1.x, s); s = fmaf(x1.y, vr1.y, s);
            s = fmaf(x1.z, vr1.z, s); s = fmaf(x1.w, vr1.w, s);
            s = fmaf(x2.x, vr2.x, s); s = fmaf(x2.y, vr2.y, s);
            s = fmaf(x2.z, vr2.z, s); s = fmaf(x2.w, vr2.w, s);
            s = fmaf(x3.x, vr3.x, s); s = fmaf(x3.y, vr3.y, s);
            s = fmaf(x3.z, vr3.z, s); s = fmaf(x3.w, vr3.w, s);
            acc[r] = s;
        }
#pragma unroll
        for (int r = 0; r < 4; ++r) {
#pragma unroll
            for (int off = 32; off >= 1; off >>= 1) acc[r] += __shfl_xor(acc[r], off, 64);
            if (lane == 0) {
                scores[r0 + r] = acc[r];
                rowsc[tile * 32 + wid * 4 + r] = acc[r];
            }
        }
    }
    __syncthreads();
    if (t < 64) {                       // wave 0: 64 row-partials -> one f64 atomic
        double e = exp((double)rowsc[t]);
#pragma unroll
        for (int off = 32; off >= 1; off >>= 1) e += __shfl_xor(e, off, 64);
        if (t == 0) atomicAdd(&denomD[b], e);
    }
}

// ---------------- K3: attn = exp(score - lse - 0.5 d^2); owner-chunk computes whole
// ctx window. Window loop is COMPILE-TIME 32 iterations (wv zero-padded, row index
// clamped) so loads pipeline instead of serializing. grid = 32 b * 8 s-chunks.
__global__ __launch_bounds__(256) void k3_out(const float* __restrict__ enc,
                                              const float* __restrict__ scores,
                                              const int* __restrict__ ts,
                                              const double* __restrict__ denomD,
                                              float* __restrict__ ctx,
                                              float* __restrict__ attn) {
    __shared__ float wv[32];
    int b = blockIdx.x >> 3;
    int c = blockIdx.x & 7;
    int t = threadIdx.x;

    float lse = (float)log(denomD[b]);
    int p = ts[b];
    float pf = (float)p;

    int s = c * 256 + t;
    float sc = scores[b * NS + s];
    float d = (float)s - pf;
    attn[(size_t)b * NS + s] = expf(sc - lse - 0.5f * d * d);

    if ((p >> 8) == c) {               // owner chunk (block-uniform): full window
        int w0 = max(0, p - WIN), w1 = min(NS - 1, p + WIN);
        const float* sb = scores + (size_t)b * NS;
        if (t < 32) {                  // zero-padded weights: exact (0 * x == 0)
            int r = w0 + t;
            float w = 0.f;
            if (r <= w1) {
                float dr = (float)r - pf;
                w = expf(sb[r] - lse - 0.5f * dr * dr);
            }
            wv[t] = w;
        }
        __syncthreads();
        const float* eb = enc + (size_t)b * NS * NH;
        float a0 = 0.f, a1 = 0.f, a2 = 0.f, a3 = 0.f;
#pragma unroll 8
        for (int r = 0; r < 32; ++r) {   // fixed bound -> pipelined loads
            float w = wv[r];
            const float* er = eb + (size_t)min(w0 + r, NS - 1) * NH;
            a0 = fmaf(w, er[t],       a0);
            a1 = fmaf(w, er[t + 256], a1);
            a2 = fmaf(w, er[t + 512], a2);
            a3 = fmaf(w, er[t + 768], a3);
        }
        ctx[b * NH + t]       = a0;
        ctx[b * NH + t + 256] = a1;
        ctx[b * NH + t + 512] = a2;
        ctx[b * NH + t + 768] = a3;
    }
}

extern "C" void kernel_launch(void* const* d_in, const int* in_sizes, int n_in,
                              void* d_out, int out_size, void* d_ws, size_t ws_size,
                              hipStream_t stream) {
    const float* enc  = (const float*)d_in[0];   // [B,S,H]
    const float* dec  = (const float*)d_in[1];   // [B,H]
    const int*   ts   = (const int*)d_in[2];     // [B]
    const float* Wa_w = (const float*)d_in[3];   // [H,H]
    // d_in[4] = Wa_b: uniform per-b score shift -> softmax-invariant, dropped.

    float* out  = (float*)d_out;
    float* ctx  = out;             // [B,H]
    float* attn = out + NB * NH;   // [B,S]

    float*  v      = (float*)d_ws;                  // NB*NH floats
    float*  scores = v + NB * NH;                   // NB*NS floats
    double* denomD = (double*)(scores + NB * NS);   // NB doubles (8B-aligned)

    k1_v     <<<128,  256, 0, stream>>>(dec, Wa_w, v, denomD);
    k2_scores<<<1024, 512, 0, stream>>>(enc, v, scores, denomD);
    k3_out   <<<NB*8, 256, 0, stream>>>(enc, scores, ts, denomD, ctx, attn);
}